// Round 1
// baseline (394.334 us; speedup 1.0000x reference)
//
#include <hip/hip_runtime.h>
#include <stdint.h>

#define B_ 4
#define S_ 2048
#define E_ 1024
#define H_ 16
#define D_ 64
#define M_ (B_*S_)   // 8192

typedef unsigned short u16;
typedef __bf16 bf16x8 __attribute__((ext_vector_type(8)));
typedef float f32x4 __attribute__((ext_vector_type(4)));
typedef u16 u16x8 __attribute__((ext_vector_type(8)));
typedef u16 u16x4 __attribute__((ext_vector_type(4)));

#define GLD16(g, l) __builtin_amdgcn_global_load_lds((const __attribute__((address_space(1))) void*)(g), (__attribute__((address_space(3))) void*)(l), 16, 0, 0)

__device__ inline u16 f2bf(float f) {
  union { float f; unsigned u; } v; v.f = f;
  unsigned u = v.u;
  unsigned r = (u + 0x7fffu + ((u >> 16) & 1u)) >> 16;
  return (u16)r;
}

// ---------------- fp32 -> bf16 convert (8 elems/thread) ----------------
__global__ void cvt_f32_bf16(const float* __restrict__ src, u16* __restrict__ dst, int n) {
  int i = (blockIdx.x * blockDim.x + threadIdx.x) * 8;
  if (i >= n) return;
  float4 a = *(const float4*)(src + i);
  float4 b = *(const float4*)(src + i + 4);
  u16x8 o;
  o[0]=f2bf(a.x); o[1]=f2bf(a.y); o[2]=f2bf(a.z); o[3]=f2bf(a.w);
  o[4]=f2bf(b.x); o[5]=f2bf(b.y); o[6]=f2bf(b.z); o[7]=f2bf(b.w);
  *(u16x8*)(dst + i) = o;
}

// ---------------- QKV projection GEMM (m97 structure) ----------------
// C[m][n] = (sum_k A[m][k]*W[n][k] + bias[n]) * scale
// A: [8192][1024] bf16, W: [1024][1024] bf16
// mode 0: out[((b*16+h)*2048+s)*64+d]  (Q/K, [BH][S][D])
// mode 1: out[((b*16+h)*64+d)*2048+s]  (V transposed, [BH][D][S])
__launch_bounds__(256)
__global__ void qkv_gemm(const u16* __restrict__ A, const u16* __restrict__ W,
                         const float* __restrict__ bias, u16* __restrict__ out,
                         float scale, int mode) {
  __shared__ u16 As[128*32];
  __shared__ u16 Bs[128*32];
  const int t = threadIdx.x;
  const int lane = t & 63;
  const int w = t >> 6;           // wave 0..3
  const int wr = w >> 1, wc = w & 1;
  const int m0 = blockIdx.x * 128;
  const int n0 = blockIdx.y * 128;
  const int l15 = lane & 15, lhi = lane >> 4;

  f32x4 acc[4][4] = {};

  for (int k0 = 0; k0 < E_; k0 += 32) {
#pragma unroll
    for (int j = 0; j < 2; ++j) {
      int eo = w*1024 + j*512 + lane*8;           // elem offset in 128x32 tile
      int row = eo >> 5, col = eo & 31;
      GLD16(A + (size_t)(m0+row)*E_ + k0 + col, As + w*1024 + j*512);
      GLD16(W + (size_t)(n0+row)*E_ + k0 + col, Bs + w*1024 + j*512);
    }
    __syncthreads();
    bf16x8 af[4], bf[4];
#pragma unroll
    for (int i = 0; i < 4; ++i)
      af[i] = *(const bf16x8*)&As[(wr*64 + i*16 + l15)*32 + lhi*8];
#pragma unroll
    for (int i = 0; i < 4; ++i)
      bf[i] = *(const bf16x8*)&Bs[(wc*64 + i*16 + l15)*32 + lhi*8];
#pragma unroll
    for (int mi = 0; mi < 4; ++mi)
#pragma unroll
      for (int ni = 0; ni < 4; ++ni)
        acc[mi][ni] = __builtin_amdgcn_mfma_f32_16x16x32_bf16(af[mi], bf[ni], acc[mi][ni], 0, 0, 0);
    __syncthreads();
  }

  // epilogue
#pragma unroll
  for (int mi = 0; mi < 4; ++mi) {
#pragma unroll
    for (int ni = 0; ni < 4; ++ni) {
      int n = n0 + wc*64 + ni*16 + l15;
      float bia = bias[n];
      int h = n >> 6, d = n & 63;
      if (mode == 0) {
#pragma unroll
        for (int j = 0; j < 4; ++j) {
          int m = m0 + wr*64 + mi*16 + lhi*4 + j;
          int b = m >> 11, s = m & 2047;
          out[((size_t)((b*H_ + h)*S_ + s))*D_ + d] = f2bf((acc[mi][ni][j] + bia) * scale);
        }
      } else {
        int m = m0 + wr*64 + mi*16 + lhi*4;
        int b = m >> 11, s = m & 2047;
        u16x4 pk;
#pragma unroll
        for (int j = 0; j < 4; ++j) pk[j] = f2bf((acc[mi][ni][j] + bia) * scale);
        *(u16x4*)&out[((size_t)((b*H_ + h)*D_ + d))*S_ + s] = pk;
      }
    }
  }
}

// ---------------- fused causal+pad flash attention ----------------
// Q,K: [BH][S][D] bf16 (Q pre-scaled by 1/sqrt(D)); Vt: [BH][D][S] bf16
// out: [B][S][E] fp32
#define QB 64
#define KB 64
__launch_bounds__(256)
__global__ void attn(const u16* __restrict__ Q, const u16* __restrict__ Kg,
                     const u16* __restrict__ Vt, const int* __restrict__ pad,
                     float* __restrict__ out) {
  __shared__ u16 Qs[QB*64];       // [64 q][64 d]
  __shared__ u16 Ks[KB*64];       // [64 kv][64 d]
  __shared__ u16 Vs[64*KB];       // [64 d][64 kv]
  __shared__ u16 Ps[4][16*64];    // per-wave P [16 q][64 kv]
  const int t = threadIdx.x, lane = t & 63, w = t >> 6;
  const int l15 = lane & 15, lhi = lane >> 4;
  const int bh = blockIdx.y, b = bh >> 4, h = bh & 15;
  const int q0 = blockIdx.x * QB;
  const int nkt = blockIdx.x + 1;   // causal: only tiles up to q-tile

  // stage Q tile (8KB contiguous)
  const u16* Qg = Q + (size_t)(bh*S_ + q0)*D_;
#pragma unroll
  for (int j = 0; j < 2; ++j) {
    int eo = j*2048 + w*512;
    GLD16(Qg + eo + lane*8, Qs + eo);
  }
  __syncthreads();
  bf16x8 qa[2];
#pragma unroll
  for (int ks = 0; ks < 2; ++ks)
    qa[ks] = *(const bf16x8*)&Qs[(w*16 + l15)*64 + ks*32 + lhi*8];

  f32x4 o[4] = {};
  float mrow[4], lrow[4];
#pragma unroll
  for (int j = 0; j < 4; ++j) { mrow[j] = -1e30f; lrow[j] = 0.f; }

  for (int kt = 0; kt < nkt; ++kt) {
    int kv0 = kt*KB;
    const u16* Kgp = Kg + (size_t)(bh*S_ + kv0)*D_;
    const u16* Vgp = Vt + (size_t)bh*D_*S_ + kv0;
#pragma unroll
    for (int j = 0; j < 2; ++j) {
      int eo = j*2048 + w*512;
      GLD16(Kgp + eo + lane*8, Ks + eo);
      int el = eo + lane*8;                    // Vt tile: row=d, col=s
      GLD16(Vgp + (size_t)(el >> 6)*S_ + (el & 63), Vs + eo);
    }
    __syncthreads();

    // S = Q K^T  (per wave: 16 q x 64 kv)
    f32x4 sc[4];
#pragma unroll
    for (int f = 0; f < 4; ++f) {
      f32x4 z = {};
#pragma unroll
      for (int ks = 0; ks < 2; ++ks) {
        bf16x8 kb = *(const bf16x8*)&Ks[(f*16 + l15)*64 + ks*32 + lhi*8];
        z = __builtin_amdgcn_mfma_f32_16x16x32_bf16(qa[ks], kb, z, 0, 0, 0);
      }
      sc[f] = z;
    }
    // mask: causal + pad[k]
#pragma unroll
    for (int f = 0; f < 4; ++f) {
      int kv = kv0 + f*16 + l15;
      int padk = pad[b*S_ + kv];
#pragma unroll
      for (int j = 0; j < 4; ++j) {
        int q = q0 + w*16 + lhi*4 + j;
        if (!padk || kv > q) sc[f][j] = -1e30f;
      }
    }
    // online softmax
    float corr[4];
#pragma unroll
    for (int j = 0; j < 4; ++j) {
      float r = fmaxf(fmaxf(sc[0][j], sc[1][j]), fmaxf(sc[2][j], sc[3][j]));
      r = fmaxf(r, __shfl_xor(r, 1));
      r = fmaxf(r, __shfl_xor(r, 2));
      r = fmaxf(r, __shfl_xor(r, 4));
      r = fmaxf(r, __shfl_xor(r, 8));
      float mn = fmaxf(mrow[j], r);
      corr[j] = exp2f((mrow[j] - mn) * 1.44269504f);
      mrow[j] = mn;
    }
    float rs[4] = {0.f, 0.f, 0.f, 0.f};
#pragma unroll
    for (int f = 0; f < 4; ++f)
#pragma unroll
      for (int j = 0; j < 4; ++j) {
        float p = exp2f((sc[f][j] - mrow[j]) * 1.44269504f);
        sc[f][j] = p;
        rs[j] += p;
      }
#pragma unroll
    for (int j = 0; j < 4; ++j) {
      float r = rs[j];
      r += __shfl_xor(r, 1); r += __shfl_xor(r, 2);
      r += __shfl_xor(r, 4); r += __shfl_xor(r, 8);
      lrow[j] = lrow[j]*corr[j] + r;
    }
#pragma unroll
    for (int df = 0; df < 4; ++df)
#pragma unroll
      for (int j = 0; j < 4; ++j)
        o[df][j] *= corr[j];
    // P -> LDS (per-wave buffer)
#pragma unroll
    for (int f = 0; f < 4; ++f)
#pragma unroll
      for (int j = 0; j < 4; ++j)
        Ps[w][(lhi*4 + j)*64 + f*16 + l15] = f2bf(sc[f][j]);
    // PV
#pragma unroll
    for (int ks = 0; ks < 2; ++ks) {
      bf16x8 pa = *(const bf16x8*)&Ps[w][l15*64 + ks*32 + lhi*8];
#pragma unroll
      for (int df = 0; df < 4; ++df) {
        bf16x8 vb = *(const bf16x8*)&Vs[(df*16 + l15)*64 + ks*32 + lhi*8];
        o[df] = __builtin_amdgcn_mfma_f32_16x16x32_bf16(pa, vb, o[df], 0, 0, 0);
      }
    }
    __syncthreads();   // protect Ks/Vs before next stage
  }

  // epilogue: divide by l, zero padded queries, write [B][S][E] fp32
#pragma unroll
  for (int j = 0; j < 4; ++j) {
    int q = q0 + w*16 + lhi*4 + j;
    int padq = pad[b*S_ + q];
    float inv = (padq && lrow[j] > 0.f) ? 1.0f / lrow[j] : 0.0f;
#pragma unroll
    for (int df = 0; df < 4; ++df) {
      int d = df*16 + l15;
      out[((size_t)(b*S_ + q))*E_ + h*D_ + d] = o[df][j] * inv;
    }
  }
}

extern "C" void kernel_launch(void* const* d_in, const int* in_sizes, int n_in,
                              void* d_out, int out_size, void* d_ws, size_t ws_size,
                              hipStream_t stream) {
  const float* X  = (const float*)d_in[0];
  const int*  pad = (const int*)d_in[1];
  const float* Wq = (const float*)d_in[2];
  const float* bq = (const float*)d_in[3];
  const float* Wk = (const float*)d_in[4];
  const float* bk = (const float*)d_in[5];
  const float* Wv = (const float*)d_in[6];
  const float* bv = (const float*)d_in[7];
  float* out = (float*)d_out;

  u16* Xb  = (u16*)d_ws;                         // 16 MB
  u16* Wb  = Xb + (size_t)M_*E_;                 // 6 MB (3 matrices)
  u16* Qb  = Wb + (size_t)3*E_*E_;               // 16 MB
  u16* Kb  = Qb + (size_t)M_*E_;                 // 16 MB
  u16* Vtb = Kb + (size_t)M_*E_;                 // 16 MB

  cvt_f32_bf16<<<4096, 256, 0, stream>>>(X,  Xb, M_*E_);
  cvt_f32_bf16<<<512,  256, 0, stream>>>(Wq, Wb,            E_*E_);
  cvt_f32_bf16<<<512,  256, 0, stream>>>(Wk, Wb +   E_*E_,  E_*E_);
  cvt_f32_bf16<<<512,  256, 0, stream>>>(Wv, Wb + 2*E_*E_,  E_*E_);

  dim3 gg(M_/128, E_/128);
  qkv_gemm<<<gg, 256, 0, stream>>>(Xb, Wb,            bq, Qb,  0.125f, 0);
  qkv_gemm<<<gg, 256, 0, stream>>>(Xb, Wb +   E_*E_,  bk, Kb,  1.0f,   0);
  qkv_gemm<<<gg, 256, 0, stream>>>(Xb, Wb + 2*E_*E_,  bv, Vtb, 1.0f,   1);

  dim3 ga(S_/QB, B_*H_);
  attn<<<ga, 256, 0, stream>>>(Qb, Kb, Vtb, pad, out);
}

// Round 2
// 298.393 us; speedup vs baseline: 1.3215x; 1.3215x over previous
//
#include <hip/hip_runtime.h>
#include <stdint.h>

#define B_ 4
#define S_ 2048
#define E_ 1024
#define H_ 16
#define D_ 64
#define M_ (B_*S_)   // 8192

typedef unsigned short u16;
typedef __bf16 bf16x8 __attribute__((ext_vector_type(8)));
typedef float f32x4 __attribute__((ext_vector_type(4)));
typedef u16 u16x8 __attribute__((ext_vector_type(8)));
typedef u16 u16x4 __attribute__((ext_vector_type(4)));

#define GLD16(g, l) __builtin_amdgcn_global_load_lds((const __attribute__((address_space(1))) void*)(g), (__attribute__((address_space(3))) void*)(l), 16, 0, 0)

__device__ inline u16 f2bf(float f) {
  union { float f; unsigned u; } v; v.f = f;
  unsigned u = v.u;
  unsigned r = (u + 0x7fffu + ((u >> 16) & 1u)) >> 16;
  return (u16)r;
}

// ---------------- fp32 -> bf16 convert (8 elems/thread) ----------------
__global__ void cvt_f32_bf16(const float* __restrict__ src, u16* __restrict__ dst, int n) {
  int i = (blockIdx.x * blockDim.x + threadIdx.x) * 8;
  if (i >= n) return;
  float4 a = *(const float4*)(src + i);
  float4 b = *(const float4*)(src + i + 4);
  u16x8 o;
  o[0]=f2bf(a.x); o[1]=f2bf(a.y); o[2]=f2bf(a.z); o[3]=f2bf(a.w);
  o[4]=f2bf(b.x); o[5]=f2bf(b.y); o[6]=f2bf(b.z); o[7]=f2bf(b.w);
  *(u16x8*)(dst + i) = o;
}

// ---------------- QKV projection GEMM (m97 structure) ----------------
__launch_bounds__(256)
__global__ void qkv_gemm(const u16* __restrict__ A, const u16* __restrict__ W,
                         const float* __restrict__ bias, u16* __restrict__ out,
                         float scale, int mode) {
  __shared__ u16 As[128*32];
  __shared__ u16 Bs[128*32];
  const int t = threadIdx.x;
  const int lane = t & 63;
  const int w = t >> 6;           // wave 0..3
  const int wr = w >> 1, wc = w & 1;
  const int m0 = blockIdx.x * 128;
  const int n0 = blockIdx.y * 128;
  const int l15 = lane & 15, lhi = lane >> 4;

  f32x4 acc[4][4] = {};

  for (int k0 = 0; k0 < E_; k0 += 32) {
#pragma unroll
    for (int j = 0; j < 2; ++j) {
      int eo = w*1024 + j*512 + lane*8;           // elem offset in 128x32 tile
      int row = eo >> 5, col = eo & 31;
      GLD16(A + (size_t)(m0+row)*E_ + k0 + col, As + w*1024 + j*512);
      GLD16(W + (size_t)(n0+row)*E_ + k0 + col, Bs + w*1024 + j*512);
    }
    __syncthreads();
    bf16x8 af[4], bf[4];
#pragma unroll
    for (int i = 0; i < 4; ++i)
      af[i] = *(const bf16x8*)&As[(wr*64 + i*16 + l15)*32 + lhi*8];
#pragma unroll
    for (int i = 0; i < 4; ++i)
      bf[i] = *(const bf16x8*)&Bs[(wc*64 + i*16 + l15)*32 + lhi*8];
#pragma unroll
    for (int mi = 0; mi < 4; ++mi)
#pragma unroll
      for (int ni = 0; ni < 4; ++ni)
        acc[mi][ni] = __builtin_amdgcn_mfma_f32_16x16x32_bf16(af[mi], bf[ni], acc[mi][ni], 0, 0, 0);
    __syncthreads();
  }

  // epilogue
#pragma unroll
  for (int mi = 0; mi < 4; ++mi) {
#pragma unroll
    for (int ni = 0; ni < 4; ++ni) {
      int n = n0 + wc*64 + ni*16 + l15;
      float bia = bias[n];
      int h = n >> 6, d = n & 63;
      if (mode == 0) {
#pragma unroll
        for (int j = 0; j < 4; ++j) {
          int m = m0 + wr*64 + mi*16 + lhi*4 + j;
          int b = m >> 11, s = m & 2047;
          out[((size_t)((b*H_ + h)*S_ + s))*D_ + d] = f2bf((acc[mi][ni][j] + bia) * scale);
        }
      } else {
        int m = m0 + wr*64 + mi*16 + lhi*4;
        int b = m >> 11, s = m & 2047;
        u16x4 pk;
#pragma unroll
        for (int j = 0; j < 4; ++j) pk[j] = f2bf((acc[mi][ni][j] + bia) * scale);
        *(u16x4*)&out[((size_t)((b*H_ + h)*D_ + d))*S_ + s] = pk;
      }
    }
  }
}

// ---------------- fused causal+pad flash attention ----------------
// Q,K: [BH][S][D] bf16 (Q pre-scaled by 1/sqrt(D)); Vt: [BH][D][S] bf16
// out: [B][S][E] fp32
// Block pairs q-tile (blockIdx.x) with q-tile (NQT-1-blockIdx.x) -> uniform work.
// LDS tiles XOR-swizzled (T2, both-sides rule #21): linear gload_lds dest,
// inverse-swizzled global source, swizzled ds_read.
#define QB 64
#define KB 64
#define NQT (S_/QB)   // 32
__launch_bounds__(256)
__global__ void attn(const u16* __restrict__ Q, const u16* __restrict__ Kg,
                     const u16* __restrict__ Vt, const int* __restrict__ pad,
                     float* __restrict__ out) {
  __shared__ u16 Qs[QB*64];       // [64 q][64 d], swizzled
  __shared__ u16 Ks[KB*64];       // [64 kv][64 d], swizzled
  __shared__ u16 Vs[64*KB];       // [64 d][64 kv], swizzled
  __shared__ u16 Ps[4][16*64];    // per-wave P [16 q][64 kv], key-swizzled
  const int t = threadIdx.x, lane = t & 63, w = t >> 6;
  const int l15 = lane & 15, lhi = lane >> 4;
  const int bh = blockIdx.y, b = bh >> 4, h = bh & 15;
  // staging swizzle: XOR on elem-offset bits 3..5; rows of the 64-wide tile
  // have (deo>>6)&7 == (lane>>3)&7 for our lane->dest mapping.
  const int lsw = ((lane >> 3) & 7) << 3;
  // fragment-read swizzle: row&7 == l15&7 for all fragment rows.
  const int x0 = ((0 + lhi) ^ (l15 & 7)) * 8;   // ks=0 col offset (elems)
  const int x1 = ((4 + lhi) ^ (l15 & 7)) * 8;   // ks=1
  const int pkey = (l15 ^ (l15 >> 1)) & 7;      // Ps read-row key

  for (int half = 0; half < 2; ++half) {
    const int qt = half ? (NQT - 1 - (int)blockIdx.x) : (int)blockIdx.x;
    const int q0 = qt * QB;
    const int nkt = qt + 1;        // causal
    __syncthreads();               // protect Qs reuse across halves

    const u16* Qg = Q + (size_t)(bh*S_ + q0)*D_;
#pragma unroll
    for (int j = 0; j < 2; ++j) {
      int eo = j*2048 + w*512;
      GLD16(Qg + ((eo + lane*8) ^ lsw), Qs + eo);
    }
    __syncthreads();
    bf16x8 qa[2];
    qa[0] = *(const bf16x8*)&Qs[(w*16 + l15)*64 + x0];
    qa[1] = *(const bf16x8*)&Qs[(w*16 + l15)*64 + x1];

    f32x4 o[4] = {};
    float mrow[4], lrow[4];
#pragma unroll
    for (int j = 0; j < 4; ++j) { mrow[j] = -1e30f; lrow[j] = 0.f; }

    for (int kt = 0; kt < nkt; ++kt) {
      int kv0 = kt*KB;
      const u16* Kgp = Kg + (size_t)(bh*S_ + kv0)*D_;
      const u16* Vgp = Vt + (size_t)bh*D_*S_ + kv0;
#pragma unroll
      for (int j = 0; j < 2; ++j) {
        int eo = j*2048 + w*512;
        int leo = (eo + lane*8) ^ lsw;
        GLD16(Kgp + leo, Ks + eo);
        GLD16(Vgp + (size_t)(leo >> 6)*S_ + (leo & 63), Vs + eo);
      }
      __syncthreads();

      // S = Q K^T  (per wave: 16 q x 64 kv)
      f32x4 sc[4];
#pragma unroll
      for (int f = 0; f < 4; ++f) {
        const u16* kr = &Ks[(f*16 + l15)*64];
        f32x4 z = {};
        z = __builtin_amdgcn_mfma_f32_16x16x32_bf16(qa[0], *(const bf16x8*)&kr[x0], z, 0, 0, 0);
        z = __builtin_amdgcn_mfma_f32_16x16x32_bf16(qa[1], *(const bf16x8*)&kr[x1], z, 0, 0, 0);
        sc[f] = z;
      }
      // mask: causal + pad[k]
#pragma unroll
      for (int f = 0; f < 4; ++f) {
        int kv = kv0 + f*16 + l15;
        int padk = pad[b*S_ + kv];
#pragma unroll
        for (int j = 0; j < 4; ++j) {
          int q = q0 + w*16 + lhi*4 + j;
          if (!padk || kv > q) sc[f][j] = -1e30f;
        }
      }
      // online softmax
      float corr[4];
#pragma unroll
      for (int j = 0; j < 4; ++j) {
        float r = fmaxf(fmaxf(sc[0][j], sc[1][j]), fmaxf(sc[2][j], sc[3][j]));
        r = fmaxf(r, __shfl_xor(r, 1));
        r = fmaxf(r, __shfl_xor(r, 2));
        r = fmaxf(r, __shfl_xor(r, 4));
        r = fmaxf(r, __shfl_xor(r, 8));
        float mn = fmaxf(mrow[j], r);
        corr[j] = exp2f((mrow[j] - mn) * 1.44269504f);
        mrow[j] = mn;
      }
      float rs[4] = {0.f, 0.f, 0.f, 0.f};
#pragma unroll
      for (int f = 0; f < 4; ++f)
#pragma unroll
        for (int j = 0; j < 4; ++j) {
          float p = exp2f((sc[f][j] - mrow[j]) * 1.44269504f);
          sc[f][j] = p;
          rs[j] += p;
        }
#pragma unroll
      for (int j = 0; j < 4; ++j) {
        float r = rs[j];
        r += __shfl_xor(r, 1); r += __shfl_xor(r, 2);
        r += __shfl_xor(r, 4); r += __shfl_xor(r, 8);
        lrow[j] = lrow[j]*corr[j] + r;
      }
#pragma unroll
      for (int df = 0; df < 4; ++df)
#pragma unroll
        for (int j = 0; j < 4; ++j)
          o[df][j] *= corr[j];
      // P -> LDS (per-wave buffer, Gray-key swizzle per row)
#pragma unroll
      for (int f = 0; f < 4; ++f)
#pragma unroll
        for (int j = 0; j < 4; ++j) {
          int row = lhi*4 + j;
          int key = (row ^ (row >> 1)) & 7;
          int blk = (f*2 + (l15 >> 3)) ^ key;
          Ps[w][row*64 + blk*8 + (l15 & 7)] = f2bf(sc[f][j]);
        }
      // PV
      bf16x8 pa0 = *(const bf16x8*)&Ps[w][l15*64 + ((0 + lhi) ^ pkey)*8];
      bf16x8 pa1 = *(const bf16x8*)&Ps[w][l15*64 + ((4 + lhi) ^ pkey)*8];
#pragma unroll
      for (int df = 0; df < 4; ++df) {
        const u16* vr = &Vs[(df*16 + l15)*64];
        o[df] = __builtin_amdgcn_mfma_f32_16x16x32_bf16(pa0, *(const bf16x8*)&vr[x0], o[df], 0, 0, 0);
        o[df] = __builtin_amdgcn_mfma_f32_16x16x32_bf16(pa1, *(const bf16x8*)&vr[x1], o[df], 0, 0, 0);
      }
      __syncthreads();   // protect Ks/Vs before next stage
    }

    // epilogue: divide by l, zero padded queries, write [B][S][E] fp32
#pragma unroll
    for (int j = 0; j < 4; ++j) {
      int q = q0 + w*16 + lhi*4 + j;
      int padq = pad[b*S_ + q];
      float inv = (padq && lrow[j] > 0.f) ? 1.0f / lrow[j] : 0.0f;
#pragma unroll
      for (int df = 0; df < 4; ++df) {
        int d = df*16 + l15;
        out[((size_t)(b*S_ + q))*E_ + h*D_ + d] = o[df][j] * inv;
      }
    }
  }
}

extern "C" void kernel_launch(void* const* d_in, const int* in_sizes, int n_in,
                              void* d_out, int out_size, void* d_ws, size_t ws_size,
                              hipStream_t stream) {
  const float* X  = (const float*)d_in[0];
  const int*  pad = (const int*)d_in[1];
  const float* Wq = (const float*)d_in[2];
  const float* bq = (const float*)d_in[3];
  const float* Wk = (const float*)d_in[4];
  const float* bk = (const float*)d_in[5];
  const float* Wv = (const float*)d_in[6];
  const float* bv = (const float*)d_in[7];
  float* out = (float*)d_out;

  u16* Xb  = (u16*)d_ws;                         // 16 MB
  u16* Wb  = Xb + (size_t)M_*E_;                 // 6 MB (3 matrices)
  u16* Qb  = Wb + (size_t)3*E_*E_;               // 16 MB
  u16* Kb  = Qb + (size_t)M_*E_;                 // 16 MB
  u16* Vtb = Kb + (size_t)M_*E_;                 // 16 MB

  cvt_f32_bf16<<<4096, 256, 0, stream>>>(X,  Xb, M_*E_);
  cvt_f32_bf16<<<512,  256, 0, stream>>>(Wq, Wb,            E_*E_);
  cvt_f32_bf16<<<512,  256, 0, stream>>>(Wk, Wb +   E_*E_,  E_*E_);
  cvt_f32_bf16<<<512,  256, 0, stream>>>(Wv, Wb + 2*E_*E_,  E_*E_);

  dim3 gg(M_/128, E_/128);
  qkv_gemm<<<gg, 256, 0, stream>>>(Xb, Wb,            bq, Qb,  0.125f, 0);
  qkv_gemm<<<gg, 256, 0, stream>>>(Xb, Wb +   E_*E_,  bk, Kb,  1.0f,   0);
  qkv_gemm<<<gg, 256, 0, stream>>>(Xb, Wb + 2*E_*E_,  bv, Vtb, 1.0f,   1);

  dim3 ga(S_/QB/2, B_*H_);
  attn<<<ga, 256, 0, stream>>>(Qb, Kb, Vtb, pad, out);
}

// Round 4
// 199.835 us; speedup vs baseline: 1.9733x; 1.4932x over previous
//
#include <hip/hip_runtime.h>
#include <stdint.h>

#define B_ 4
#define S_ 2048
#define E_ 1024
#define H_ 16
#define D_ 64
#define M_ (B_*S_)   // 8192

typedef unsigned short u16;
typedef __bf16 bf16x8 __attribute__((ext_vector_type(8)));
typedef __bf16 bf16x4 __attribute__((ext_vector_type(4)));
typedef float f32x4 __attribute__((ext_vector_type(4)));
typedef u16 u16x8 __attribute__((ext_vector_type(8)));

#define GLD16(g, l) __builtin_amdgcn_global_load_lds((const __attribute__((address_space(1))) void*)(g), (__attribute__((address_space(3))) void*)(l), 16, 0, 0)

__device__ inline float fexp2(float x) {
#if __has_builtin(__builtin_amdgcn_exp2f)
  return __builtin_amdgcn_exp2f(x);
#else
  return exp2f(x);
#endif
}

__device__ inline u16 f2bf(float f) {
  union { __bf16 b; u16 u; } cv; cv.b = (__bf16)f; return cv.u;
}

// ---------------- fp32 -> bf16 convert (8 elems/thread) ----------------
__global__ void cvt_f32_bf16(const float* __restrict__ src, u16* __restrict__ dst, int n) {
  int i = (blockIdx.x * blockDim.x + threadIdx.x) * 8;
  if (i >= n) return;
  float4 a = *(const float4*)(src + i);
  float4 b = *(const float4*)(src + i + 4);
  u16x8 o;
  o[0]=f2bf(a.x); o[1]=f2bf(a.y); o[2]=f2bf(a.z); o[3]=f2bf(a.w);
  o[4]=f2bf(b.x); o[5]=f2bf(b.y); o[6]=f2bf(b.z); o[7]=f2bf(b.w);
  *(u16x8*)(dst + i) = o;
}

// ---------------- pad int -> float ----------------
__global__ void cvt_pad(const int* __restrict__ pad, float* __restrict__ padf, int n) {
  int i = blockIdx.x * blockDim.x + threadIdx.x;
  if (i < n) padf[i] = (float)pad[i];
}

// ---------------- QKV projection GEMM (m97 structure + 2-phase dbuf) ----------------
__launch_bounds__(256)
__global__ void qkv_gemm(const u16* __restrict__ A, const u16* __restrict__ W,
                         const float* __restrict__ bias, u16* __restrict__ out,
                         float scale, int mode) {
  __shared__ __align__(16) u16 As[2*128*32];
  __shared__ __align__(16) u16 Bs[2*128*32];
  const int t = threadIdx.x;
  const int lane = t & 63;
  const int w = t >> 6;           // wave 0..3
  const int wr = w >> 1, wc = w & 1;
  const int m0 = blockIdx.x * 128;
  const int n0 = blockIdx.y * 128;
  const int l15 = lane & 15, lhi = lane >> 4;

  f32x4 acc[4][4] = {};

  auto stage = [&](int bufi, int k0) {
#pragma unroll
    for (int j = 0; j < 2; ++j) {
      int eo = w*1024 + j*512 + lane*8;
      int row = eo >> 5, col = eo & 31;
      GLD16(A + (size_t)(m0+row)*E_ + k0 + col, As + bufi*4096 + w*1024 + j*512);
      GLD16(W + (size_t)(n0+row)*E_ + k0 + col, Bs + bufi*4096 + w*1024 + j*512);
    }
  };

  stage(0, 0);
  __syncthreads();
  for (int kt = 0; kt < E_/32; ++kt) {
    if (kt + 1 < E_/32) stage((kt+1)&1, (kt+1)*32);
    const u16* Ab = As + (kt&1)*4096;
    const u16* Bb = Bs + (kt&1)*4096;
    bf16x8 af[4], bf[4];
#pragma unroll
    for (int i = 0; i < 4; ++i)
      af[i] = *(const bf16x8*)&Ab[(wr*64 + i*16 + l15)*32 + lhi*8];
#pragma unroll
    for (int i = 0; i < 4; ++i)
      bf[i] = *(const bf16x8*)&Bb[(wc*64 + i*16 + l15)*32 + lhi*8];
#pragma unroll
    for (int mi = 0; mi < 4; ++mi)
#pragma unroll
      for (int ni = 0; ni < 4; ++ni)
        acc[mi][ni] = __builtin_amdgcn_mfma_f32_16x16x32_bf16(af[mi], bf[ni], acc[mi][ni], 0, 0, 0);
    __syncthreads();
  }

  // epilogue
#pragma unroll
  for (int mi = 0; mi < 4; ++mi) {
#pragma unroll
    for (int ni = 0; ni < 4; ++ni) {
      int n = n0 + wc*64 + ni*16 + l15;
      float bia = bias[n];
      int h = n >> 6, d = n & 63;
      if (mode == 0) {
#pragma unroll
        for (int j = 0; j < 4; ++j) {
          int m = m0 + wr*64 + mi*16 + lhi*4 + j;
          int b = m >> 11, s = m & 2047;
          out[((size_t)((b*H_ + h)*S_ + s))*D_ + d] = f2bf((acc[mi][ni][j] + bia) * scale);
        }
      } else {
        int m = m0 + wr*64 + mi*16 + lhi*4;
        int b = m >> 11, s = m & 2047;
        u16 pk0 = f2bf((acc[mi][ni][0] + bia) * scale);
        u16 pk1 = f2bf((acc[mi][ni][1] + bia) * scale);
        u16 pk2 = f2bf((acc[mi][ni][2] + bia) * scale);
        u16 pk3 = f2bf((acc[mi][ni][3] + bia) * scale);
        u16* p = &out[((size_t)((b*H_ + h)*D_ + d))*S_ + s];
        p[0]=pk0; p[1]=pk1; p[2]=pk2; p[3]=pk3;
      }
    }
  }
}

// ---------------- fused causal+pad flash attention ----------------
// Q,K: [BH][S][D] bf16 (Q pre-scaled by log2e/sqrt(D)); Vt: [BH][D][S] bf16
// Swapped QK^T: sc[f][j] = S[q_local = w*16+l15][kv_local = f*16+lhi*4+j]
#define QB 64
#define KB 64
#define NQT (S_/QB)   // 32
__launch_bounds__(256)
__global__ void attn(const u16* __restrict__ Q, const u16* __restrict__ Kg,
                     const u16* __restrict__ Vt, const float* __restrict__ padf,
                     float* __restrict__ out) {
  __shared__ __align__(16) u16 Ks[2*KB*64];   // 2 x [64 kv][64 d], swizzled
  __shared__ __align__(16) u16 Vs[2*64*KB];   // 2 x [64 d][64 kv], swizzled
  __shared__ __align__(16) u16 Ps[4*16*64];   // per-wave P [16 q][64 kv], swizzled
  const int t = threadIdx.x, lane = t & 63, w = t >> 6;
  const int l15 = lane & 15, lhi = lane >> 4;
  const int bh = blockIdx.y, b = bh >> 4, h = bh & 15;
  const int lsw = ((lane >> 3) & 7) << 3;     // staging swizzle (elem units)
  const int key = l15 & 7;
  const int x0 = ((0 + lhi) ^ key) * 8;       // K/V fragment col offsets (elems)
  const int x1 = ((4 + lhi) ^ key) * 8;
  // Ps offsets (elem units); XOR key on byte bits 4..6
  const int pw = w*1024 + l15*64;
  const int pxk = key << 4;
  int pwr[4], prd0, prd1;
#pragma unroll
  for (int f = 0; f < 4; ++f) pwr[f] = pw + (((f*32 + lhi*8) ^ pxk) >> 1);
  prd0 = pw + (((      lhi*16) ^ pxk) >> 1);
  prd1 = pw + (((64 +  lhi*16) ^ pxk) >> 1);

  const float* padb = padf + b*S_;

  auto stage = [&](int bufi, int kv0) {
#pragma unroll
    for (int j = 0; j < 2; ++j) {
      int eo = j*2048 + w*512;
      int leo = (eo + lane*8) ^ lsw;
      GLD16(Kg + (size_t)(bh*S_ + kv0)*D_ + leo, Ks + bufi*4096 + eo);
      GLD16(Vt + (size_t)bh*D_*S_ + (size_t)(leo >> 6)*S_ + kv0 + (leo & 63), Vs + bufi*4096 + eo);
    }
  };

  for (int half = 0; half < 2; ++half) {
    const int qt = half ? (NQT - 1 - (int)blockIdx.x) : (int)blockIdx.x;
    const int q0 = qt * QB;
    const int nkt = qt + 1;

    // Q fragments direct from global (read exactly once)
    const u16* Qrow = Q + (size_t)(bh*S_ + q0 + w*16 + l15)*D_;
    bf16x8 qa0 = *(const bf16x8*)(Qrow + lhi*8);
    bf16x8 qa1 = *(const bf16x8*)(Qrow + 32 + lhi*8);

    f32x4 o[4] = {};
    float mrow = -1e30f, lrow = 0.f;

    stage(0, 0);
    __syncthreads();
    for (int kt = 0; kt < nkt; ++kt) {
      if (kt + 1 < nkt) stage((kt+1)&1, (kt+1)*KB);
      const u16* Kb_ = Ks + (kt&1)*4096;
      const u16* Vb_ = Vs + (kt&1)*4096;
      const int kv0 = kt*KB;

      // S^T = K Q^T : lane holds sc[f][j] = S[q_local=w*16+l15][kv_local=f*16+lhi*4+j]
      f32x4 sc[4];
#pragma unroll
      for (int f = 0; f < 4; ++f) {
        const u16* kr = Kb_ + (f*16 + l15)*64;
        f32x4 z = {};
        z = __builtin_amdgcn_mfma_f32_16x16x32_bf16(*(const bf16x8*)(kr + x0), qa0, z, 0, 0, 0);
        z = __builtin_amdgcn_mfma_f32_16x16x32_bf16(*(const bf16x8*)(kr + x1), qa1, z, 0, 0, 0);
        sc[f] = z;
      }
      // causal mask only on the diagonal tile (q_local = w*16 + l15 !)
      if (kt == nkt - 1) {
        const int ql = w*16 + l15;
#pragma unroll
        for (int f = 0; f < 4; ++f)
#pragma unroll
          for (int j = 0; j < 4; ++j)
            if (f*16 + lhi*4 + j > ql) sc[f][j] = -1e30f;
      }
      // row max: in-lane 16 then cross-lhi
      float pmax = sc[0][0];
#pragma unroll
      for (int f = 0; f < 4; ++f)
#pragma unroll
        for (int j = 0; j < 4; ++j) pmax = fmaxf(pmax, sc[f][j]);
      pmax = fmaxf(pmax, __shfl_xor(pmax, 16));
      pmax = fmaxf(pmax, __shfl_xor(pmax, 32));
      // defer-max: rescale only when max grew by > 8 (log2 domain)
      if (__any(pmax > mrow + 8.0f)) {
        float mnew = fmaxf(mrow, pmax);
        float corr = fexp2(mrow - mnew);
        mrow = mnew;
        lrow *= corr;
        float cr[4];
#pragma unroll
        for (int j = 0; j < 4; ++j) cr[j] = __shfl(corr, lhi*4 + j);
#pragma unroll
        for (int df = 0; df < 4; ++df)
#pragma unroll
          for (int j = 0; j < 4; ++j) o[df][j] *= cr[j];
      }
      // exp2 + pad multiply + pack P
      float tsum = 0.f;
#pragma unroll
      for (int f = 0; f < 4; ++f) {
        float4 pf = *(const float4*)(padb + kv0 + f*16 + lhi*4);
        bf16x4 pk;
        float p0 = fexp2(sc[f][0] - mrow) * pf.x;
        float p1 = fexp2(sc[f][1] - mrow) * pf.y;
        float p2 = fexp2(sc[f][2] - mrow) * pf.z;
        float p3 = fexp2(sc[f][3] - mrow) * pf.w;
        tsum += p0 + p1 + p2 + p3;
        pk[0] = (__bf16)p0; pk[1] = (__bf16)p1; pk[2] = (__bf16)p2; pk[3] = (__bf16)p3;
        *(bf16x4*)(Ps + pwr[f]) = pk;
      }
      tsum += __shfl_xor(tsum, 16);
      tsum += __shfl_xor(tsum, 32);
      lrow += tsum;
      // PV
      bf16x8 pa0 = *(const bf16x8*)(Ps + prd0);
      bf16x8 pa1 = *(const bf16x8*)(Ps + prd1);
#pragma unroll
      for (int df = 0; df < 4; ++df) {
        const u16* vr = Vb_ + (df*16 + l15)*64;
        o[df] = __builtin_amdgcn_mfma_f32_16x16x32_bf16(pa0, *(const bf16x8*)(vr + x0), o[df], 0, 0, 0);
        o[df] = __builtin_amdgcn_mfma_f32_16x16x32_bf16(pa1, *(const bf16x8*)(vr + x1), o[df], 0, 0, 0);
      }
      __syncthreads();
    }

    // epilogue
#pragma unroll
    for (int j = 0; j < 4; ++j) {
      int q = q0 + w*16 + lhi*4 + j;
      float lr = __shfl(lrow, lhi*4 + j);
      float pq = padb[q];
      float inv = (lr > 0.f) ? pq / lr : 0.f;
#pragma unroll
      for (int df = 0; df < 4; ++df)
        out[((size_t)(b*S_ + q))*E_ + h*D_ + df*16 + l15] = o[df][j] * inv;
    }
  }
}

extern "C" void kernel_launch(void* const* d_in, const int* in_sizes, int n_in,
                              void* d_out, int out_size, void* d_ws, size_t ws_size,
                              hipStream_t stream) {
  const float* X  = (const float*)d_in[0];
  const int*  pad = (const int*)d_in[1];
  const float* Wq = (const float*)d_in[2];
  const float* bq = (const float*)d_in[3];
  const float* Wk = (const float*)d_in[4];
  const float* bk = (const float*)d_in[5];
  const float* Wv = (const float*)d_in[6];
  const float* bv = (const float*)d_in[7];
  float* out = (float*)d_out;

  u16* Xb  = (u16*)d_ws;                         // 16 MB
  u16* Wb  = Xb + (size_t)M_*E_;                 // 6 MB (3 matrices)
  u16* Qb  = Wb + (size_t)3*E_*E_;               // 16 MB
  u16* Kb  = Qb + (size_t)M_*E_;                 // 16 MB
  u16* Vtb = Kb + (size_t)M_*E_;                 // 16 MB
  float* padfb = (float*)(Vtb + (size_t)M_*E_);  // 32 KB

  cvt_f32_bf16<<<4096, 256, 0, stream>>>(X,  Xb, M_*E_);
  cvt_f32_bf16<<<512,  256, 0, stream>>>(Wq, Wb,            E_*E_);
  cvt_f32_bf16<<<512,  256, 0, stream>>>(Wk, Wb +   E_*E_,  E_*E_);
  cvt_f32_bf16<<<512,  256, 0, stream>>>(Wv, Wb + 2*E_*E_,  E_*E_);
  cvt_pad<<<32, 256, 0, stream>>>(pad, padfb, B_*S_);

  dim3 gg(M_/128, E_/128);
  // Q pre-scaled by (1/sqrt(D)) * log2(e) so attention exp is pure exp2
  qkv_gemm<<<gg, 256, 0, stream>>>(Xb, Wb,            bq, Qb,  0.18033688f, 0);
  qkv_gemm<<<gg, 256, 0, stream>>>(Xb, Wb +   E_*E_,  bk, Kb,  1.0f,        0);
  qkv_gemm<<<gg, 256, 0, stream>>>(Xb, Wb + 2*E_*E_,  bv, Vtb, 1.0f,        1);

  dim3 ga(S_/QB/2, B_*H_);
  attn<<<ga, 256, 0, stream>>>(Qb, Kb, Vtb, padfb, out);
}

// Round 5
// 183.427 us; speedup vs baseline: 2.1498x; 1.0895x over previous
//
#include <hip/hip_runtime.h>
#include <stdint.h>

#define B_ 4
#define S_ 2048
#define E_ 1024
#define H_ 16
#define D_ 64
#define M_ (B_*S_)   // 8192

typedef unsigned short u16;
typedef __bf16 bf16x8 __attribute__((ext_vector_type(8)));
typedef __bf16 bf16x4 __attribute__((ext_vector_type(4)));
typedef float f32x4 __attribute__((ext_vector_type(4)));
typedef u16 u16x8 __attribute__((ext_vector_type(8)));

#define GLD16(g, l) __builtin_amdgcn_global_load_lds((const __attribute__((address_space(1))) void*)(g), (__attribute__((address_space(3))) void*)(l), 16, 0, 0)

__device__ inline float fexp2(float x) {
#if __has_builtin(__builtin_amdgcn_exp2f)
  return __builtin_amdgcn_exp2f(x);
#else
  return exp2f(x);
#endif
}

__device__ inline u16 f2bf(float f) {
  union { __bf16 b; u16 u; } cv; cv.b = (__bf16)f; return cv.u;
}

// ---------------- fp32 -> bf16 convert (8 elems/thread) ----------------
__global__ void cvt_f32_bf16(const float* __restrict__ src, u16* __restrict__ dst, int n) {
  int i = (blockIdx.x * blockDim.x + threadIdx.x) * 8;
  if (i >= n) return;
  float4 a = *(const float4*)(src + i);
  float4 b = *(const float4*)(src + i + 4);
  u16x8 o;
  o[0]=f2bf(a.x); o[1]=f2bf(a.y); o[2]=f2bf(a.z); o[3]=f2bf(a.w);
  o[4]=f2bf(b.x); o[5]=f2bf(b.y); o[6]=f2bf(b.z); o[7]=f2bf(b.w);
  *(u16x8*)(dst + i) = o;
}

// ---------------- pad int -> float ----------------
__global__ void cvt_pad(const int* __restrict__ pad, float* __restrict__ padf, int n) {
  int i = blockIdx.x * blockDim.x + threadIdx.x;
  if (i < n) padf[i] = (float)pad[i];
}

// ---------------- QKV projection GEMM (m97 structure + 2-phase dbuf) ----------------
// 1D grid, XCD-chunked: xcd r owns m-blocks [r*8, r*8+8) for all n-blocks.
__launch_bounds__(256)
__global__ void qkv_gemm(const u16* __restrict__ A, const u16* __restrict__ W,
                         const float* __restrict__ bias, u16* __restrict__ out,
                         float scale, int mode) {
  __shared__ __align__(16) u16 As[2*128*32];
  __shared__ __align__(16) u16 Bs[2*128*32];
  const int t = threadIdx.x;
  const int lane = t & 63;
  const int w = t >> 6;           // wave 0..3
  const int wr = w >> 1, wc = w & 1;
  const int l = blockIdx.x;       // 512 blocks
  const int r = l & 7, s = l >> 3;
  const int m0 = (r*8 + (s & 7)) * 128;
  const int n0 = (s >> 3) * 128;
  const int l15 = lane & 15, lhi = lane >> 4;

  f32x4 acc[4][4] = {};

  auto stage = [&](int bufi, int k0) {
#pragma unroll
    for (int j = 0; j < 2; ++j) {
      int eo = w*1024 + j*512 + lane*8;
      int row = eo >> 5, col = eo & 31;
      GLD16(A + (size_t)(m0+row)*E_ + k0 + col, As + bufi*4096 + w*1024 + j*512);
      GLD16(W + (size_t)(n0+row)*E_ + k0 + col, Bs + bufi*4096 + w*1024 + j*512);
    }
  };

  stage(0, 0);
  __syncthreads();
  for (int kt = 0; kt < E_/32; ++kt) {
    if (kt + 1 < E_/32) stage((kt+1)&1, (kt+1)*32);
    const u16* Ab = As + (kt&1)*4096;
    const u16* Bb = Bs + (kt&1)*4096;
    bf16x8 af[4], bfr[4];
#pragma unroll
    for (int i = 0; i < 4; ++i)
      af[i] = *(const bf16x8*)&Ab[(wr*64 + i*16 + l15)*32 + lhi*8];
#pragma unroll
    for (int i = 0; i < 4; ++i)
      bfr[i] = *(const bf16x8*)&Bb[(wc*64 + i*16 + l15)*32 + lhi*8];
#pragma unroll
    for (int mi = 0; mi < 4; ++mi)
#pragma unroll
      for (int ni = 0; ni < 4; ++ni)
        acc[mi][ni] = __builtin_amdgcn_mfma_f32_16x16x32_bf16(af[mi], bfr[ni], acc[mi][ni], 0, 0, 0);
    __syncthreads();
  }

  // epilogue
#pragma unroll
  for (int mi = 0; mi < 4; ++mi) {
#pragma unroll
    for (int ni = 0; ni < 4; ++ni) {
      int n = n0 + wc*64 + ni*16 + l15;
      float bia = bias[n];
      int h = n >> 6, d = n & 63;
      if (mode == 0) {
#pragma unroll
        for (int j = 0; j < 4; ++j) {
          int m = m0 + wr*64 + mi*16 + lhi*4 + j;
          int b = m >> 11, sq = m & 2047;
          out[((size_t)((b*H_ + h)*S_ + sq))*D_ + d] = f2bf((acc[mi][ni][j] + bia) * scale);
        }
      } else {
        int m = m0 + wr*64 + mi*16 + lhi*4;
        int b = m >> 11, sq = m & 2047;
        u16 pk0 = f2bf((acc[mi][ni][0] + bia) * scale);
        u16 pk1 = f2bf((acc[mi][ni][1] + bia) * scale);
        u16 pk2 = f2bf((acc[mi][ni][2] + bia) * scale);
        u16 pk3 = f2bf((acc[mi][ni][3] + bia) * scale);
        u16* p = &out[((size_t)((b*H_ + h)*D_ + d))*S_ + sq];
        p[0]=pk0; p[1]=pk1; p[2]=pk2; p[3]=pk3;
      }
    }
  }
}

// ---------------- fused causal+pad flash attention ----------------
// Q,K: [BH][S][D] bf16 (Q pre-scaled by log2e/sqrt(D)); Vt: [BH][D][S] bf16
// QB=128 (8 waves), KB=64. 1D grid, XCD-local per head: bh%8 == xcd.
// Swapped QK^T: sc[f][j] = S[q_local = w*16+l15][kv_local = f*16+lhi*4+j]
#define QB 128
#define KB 64
#define NQT (S_/QB)   // 16
__launch_bounds__(512)
__global__ void attn(const u16* __restrict__ Q, const u16* __restrict__ Kg,
                     const u16* __restrict__ Vt, const float* __restrict__ padf,
                     float* __restrict__ out) {
  __shared__ __align__(16) u16 Ks[2*KB*64];   // 2 x [64 kv][64 d], swizzled
  __shared__ __align__(16) u16 Vs[2*64*KB];   // 2 x [64 d][64 kv], swizzled
  __shared__ __align__(16) u16 Ps[8*16*64];   // per-wave P [16 q][64 kv], swizzled
  const int t = threadIdx.x, lane = t & 63, w = t >> 6;   // w 0..7
  const int l15 = lane & 15, lhi = lane >> 4;
  // XCD-local decode: xcd = l&7 gets heads bh ≡ xcd (mod 8)
  const int l = blockIdx.x;                   // 512 blocks
  const int bh = (l & 7) + 8 * (l >> 6);
  const int xt = (l >> 3) & 7;                // q-tile pair index 0..7
  const int b = bh >> 4, h = bh & 15;
  const int lsw = ((lane >> 3) & 7) << 3;     // staging swizzle (elem units)
  const int key = l15 & 7;
  const int x0 = ((0 + lhi) ^ key) * 8;       // K/V fragment col offsets (elems)
  const int x1 = ((4 + lhi) ^ key) * 8;
  // Ps offsets (elem units); XOR key on byte bits 4..6
  const int pw = w*1024 + l15*64;
  const int pxk = key << 4;
  int pwr[4], prd0, prd1;
#pragma unroll
  for (int f = 0; f < 4; ++f) pwr[f] = pw + (((f*32 + lhi*8) ^ pxk) >> 1);
  prd0 = pw + (((      lhi*16) ^ pxk) >> 1);
  prd1 = pw + (((64 +  lhi*16) ^ pxk) >> 1);

  const float* padb = padf + b*S_;

  auto stage = [&](int bufi, int kv0) {
    int eo = t*8;                             // 512 threads x 8 elems = 4096
    int leo = eo ^ lsw;
    GLD16(Kg + (size_t)(bh*S_ + kv0)*D_ + leo, Ks + bufi*4096 + eo);
    GLD16(Vt + (size_t)bh*D_*S_ + (size_t)(leo >> 6)*S_ + kv0 + (leo & 63), Vs + bufi*4096 + eo);
  };

  for (int half = 0; half < 2; ++half) {
    const int qt = half ? (NQT - 1 - xt) : xt;
    const int q0 = qt * QB;
    const int nkt = 2*(qt + 1);               // KB=64 tiles covering [0, q0+QB)

    // Q fragments direct from global (read exactly once)
    const u16* Qrow = Q + (size_t)(bh*S_ + q0 + w*16 + l15)*D_;
    bf16x8 qa0 = *(const bf16x8*)(Qrow + lhi*8);
    bf16x8 qa1 = *(const bf16x8*)(Qrow + 32 + lhi*8);

    f32x4 o[4] = {};
    float mrow = -1e30f, lrow = 0.f;

    stage(0, 0);
    __syncthreads();
    for (int kt = 0; kt < nkt; ++kt) {
      if (kt + 1 < nkt) stage((kt+1)&1, (kt+1)*KB);
      const u16* Kb_ = Ks + (kt&1)*4096;
      const u16* Vb_ = Vs + (kt&1)*4096;
      const int kv0 = kt*KB;

      // S^T = K Q^T : lane holds sc[f][j] = S[q_local][kv_local=f*16+lhi*4+j]
      f32x4 sc[4];
#pragma unroll
      for (int f = 0; f < 4; ++f) {
        const u16* kr = Kb_ + (f*16 + l15)*64;
        f32x4 z = {};
        z = __builtin_amdgcn_mfma_f32_16x16x32_bf16(*(const bf16x8*)(kr + x0), qa0, z, 0, 0, 0);
        z = __builtin_amdgcn_mfma_f32_16x16x32_bf16(*(const bf16x8*)(kr + x1), qa1, z, 0, 0, 0);
        sc[f] = z;
      }
      // causal mask on the last two tiles (q_local = w*16 + l15)
      if (kt >= nkt - 2) {
        const int rel = q0 + w*16 + l15 - kv0;   // mask kv_local > rel
#pragma unroll
        for (int f = 0; f < 4; ++f)
#pragma unroll
          for (int j = 0; j < 4; ++j)
            if (f*16 + lhi*4 + j > rel) sc[f][j] = -1e30f;
      }
      // row max: in-lane 16 then cross-lhi
      float pmax = sc[0][0];
#pragma unroll
      for (int f = 0; f < 4; ++f)
#pragma unroll
        for (int j = 0; j < 4; ++j) pmax = fmaxf(pmax, sc[f][j]);
      pmax = fmaxf(pmax, __shfl_xor(pmax, 16));
      pmax = fmaxf(pmax, __shfl_xor(pmax, 32));
      // defer-max: rescale only when max grew by > 8 (log2 domain)
      if (__any(pmax > mrow + 8.0f)) {
        float mnew = fmaxf(mrow, pmax);
        float corr = fexp2(mrow - mnew);
        mrow = mnew;
        lrow *= corr;
        float cr[4];
#pragma unroll
        for (int j = 0; j < 4; ++j) cr[j] = __shfl(corr, lhi*4 + j);
#pragma unroll
        for (int df = 0; df < 4; ++df)
#pragma unroll
          for (int j = 0; j < 4; ++j) o[df][j] *= cr[j];
      }
      // exp2 + pad multiply + pack P
      float tsum = 0.f;
#pragma unroll
      for (int f = 0; f < 4; ++f) {
        float4 pf = *(const float4*)(padb + kv0 + f*16 + lhi*4);
        bf16x4 pk;
        float p0 = fexp2(sc[f][0] - mrow) * pf.x;
        float p1 = fexp2(sc[f][1] - mrow) * pf.y;
        float p2 = fexp2(sc[f][2] - mrow) * pf.z;
        float p3 = fexp2(sc[f][3] - mrow) * pf.w;
        tsum += p0 + p1 + p2 + p3;
        pk[0] = (__bf16)p0; pk[1] = (__bf16)p1; pk[2] = (__bf16)p2; pk[3] = (__bf16)p3;
        *(bf16x4*)(Ps + pwr[f]) = pk;
      }
      tsum += __shfl_xor(tsum, 16);
      tsum += __shfl_xor(tsum, 32);
      lrow += tsum;
      // PV
      bf16x8 pa0 = *(const bf16x8*)(Ps + prd0);
      bf16x8 pa1 = *(const bf16x8*)(Ps + prd1);
#pragma unroll
      for (int df = 0; df < 4; ++df) {
        const u16* vr = Vb_ + (df*16 + l15)*64;
        o[df] = __builtin_amdgcn_mfma_f32_16x16x32_bf16(pa0, *(const bf16x8*)(vr + x0), o[df], 0, 0, 0);
        o[df] = __builtin_amdgcn_mfma_f32_16x16x32_bf16(pa1, *(const bf16x8*)(vr + x1), o[df], 0, 0, 0);
      }
      __syncthreads();
    }

    // epilogue
#pragma unroll
    for (int j = 0; j < 4; ++j) {
      int q = q0 + w*16 + lhi*4 + j;
      float lr = __shfl(lrow, lhi*4 + j);
      float pq = padb[q];
      float inv = (lr > 0.f) ? pq / lr : 0.f;
#pragma unroll
      for (int df = 0; df < 4; ++df)
        out[((size_t)(b*S_ + q))*E_ + h*D_ + df*16 + l15] = o[df][j] * inv;
    }
  }
}

extern "C" void kernel_launch(void* const* d_in, const int* in_sizes, int n_in,
                              void* d_out, int out_size, void* d_ws, size_t ws_size,
                              hipStream_t stream) {
  const float* X  = (const float*)d_in[0];
  const int*  pad = (const int*)d_in[1];
  const float* Wq = (const float*)d_in[2];
  const float* bq = (const float*)d_in[3];
  const float* Wk = (const float*)d_in[4];
  const float* bk = (const float*)d_in[5];
  const float* Wv = (const float*)d_in[6];
  const float* bv = (const float*)d_in[7];
  float* out = (float*)d_out;

  u16* Xb  = (u16*)d_ws;                         // 16 MB
  u16* Wb  = Xb + (size_t)M_*E_;                 // 6 MB (3 matrices)
  u16* Qb  = Wb + (size_t)3*E_*E_;               // 16 MB
  u16* Kb  = Qb + (size_t)M_*E_;                 // 16 MB
  u16* Vtb = Kb + (size_t)M_*E_;                 // 16 MB
  float* padfb = (float*)(Vtb + (size_t)M_*E_);  // 32 KB

  cvt_f32_bf16<<<4096, 256, 0, stream>>>(X,  Xb, M_*E_);
  cvt_f32_bf16<<<512,  256, 0, stream>>>(Wq, Wb,            E_*E_);
  cvt_f32_bf16<<<512,  256, 0, stream>>>(Wk, Wb +   E_*E_,  E_*E_);
  cvt_f32_bf16<<<512,  256, 0, stream>>>(Wv, Wb + 2*E_*E_,  E_*E_);
  cvt_pad<<<32, 256, 0, stream>>>(pad, padfb, B_*S_);

  // Q pre-scaled by (1/sqrt(D)) * log2(e) so attention exp is pure exp2
  qkv_gemm<<<512, 256, 0, stream>>>(Xb, Wb,            bq, Qb,  0.18033688f, 0);
  qkv_gemm<<<512, 256, 0, stream>>>(Xb, Wb +   E_*E_,  bk, Kb,  1.0f,        0);
  qkv_gemm<<<512, 256, 0, stream>>>(Xb, Wb + 2*E_*E_,  bv, Vtb, 1.0f,        1);

  attn<<<512, 512, 0, stream>>>(Qb, Kb, Vtb, padfb, out);
}

// Round 6
// 143.491 us; speedup vs baseline: 2.7481x; 1.2783x over previous
//
#include <hip/hip_runtime.h>
#include <stdint.h>

#define B_ 4
#define S_ 2048
#define E_ 1024
#define H_ 16
#define D_ 64
#define M_ (B_*S_)   // 8192

typedef unsigned short u16;
typedef __bf16 bf16x8 __attribute__((ext_vector_type(8)));
typedef __bf16 bf16x4 __attribute__((ext_vector_type(4)));
typedef float f32x4 __attribute__((ext_vector_type(4)));
typedef u16 u16x8 __attribute__((ext_vector_type(8)));

#define GLD16(g, l) __builtin_amdgcn_global_load_lds((const __attribute__((address_space(1))) void*)(g), (__attribute__((address_space(3))) void*)(l), 16, 0, 0)

__device__ inline float fexp2(float x) {
#if __has_builtin(__builtin_amdgcn_exp2f)
  return __builtin_amdgcn_exp2f(x);
#else
  return exp2f(x);
#endif
}

__device__ inline u16 f2bf(float f) {
  union { __bf16 b; u16 u; } cv; cv.b = (__bf16)f; return cv.u;
}

// ---------------- all converts in one launch ----------------
__device__ inline void cvt8(const float* __restrict__ src, u16* __restrict__ dst, int i) {
  float4 a = *(const float4*)(src + i);
  float4 b = *(const float4*)(src + i + 4);
  u16x8 o;
  o[0]=f2bf(a.x); o[1]=f2bf(a.y); o[2]=f2bf(a.z); o[3]=f2bf(a.w);
  o[4]=f2bf(b.x); o[5]=f2bf(b.y); o[6]=f2bf(b.z); o[7]=f2bf(b.w);
  *(u16x8*)(dst + i) = o;
}

// blocks: [0,4096) X | [4096,5632) Wq/Wk/Wv (512 each) | [5632,5664) pad
__global__ void cvt_all(const float* __restrict__ X, const float* __restrict__ Wq,
                        const float* __restrict__ Wk, const float* __restrict__ Wv,
                        const int* __restrict__ pad,
                        u16* __restrict__ Xb, u16* __restrict__ Wb,
                        float* __restrict__ padf) {
  const int bi = blockIdx.x;
  if (bi < 4096) {
    cvt8(X, Xb, bi*2048 + threadIdx.x*8);
  } else if (bi < 5632) {
    int r = bi - 4096;
    int mat = r >> 9, j = r & 511;
    const float* src = (mat == 0) ? Wq : (mat == 1) ? Wk : Wv;
    cvt8(src, Wb + (size_t)mat*E_*E_, j*2048 + threadIdx.x*8);
  } else {
    int i = (bi - 5632)*256 + threadIdx.x;
    padf[i] = (float)pad[i];
  }
}

// ---------------- fused QKV projection GEMM (3 matrices, one launch) ----------------
// 1536 blocks: xcd = l&7; s = l>>3 in [0,192): mat = s>>6, inner = s&63
// m0 = (xcd*8 + inner&7)*128, n0 = (inner>>3)*128  -> per-XCD L2-resident panels.
__launch_bounds__(256)
__global__ void qkv_gemm3(const u16* __restrict__ A, const u16* __restrict__ Wall,
                          const float* __restrict__ bq, const float* __restrict__ bk,
                          const float* __restrict__ bv,
                          u16* __restrict__ Qb, u16* __restrict__ Kb, u16* __restrict__ Vtb,
                          float qscale) {
  __shared__ __align__(16) u16 As[2*128*32];
  __shared__ __align__(16) u16 Bs[2*128*32];
  const int t = threadIdx.x;
  const int lane = t & 63;
  const int w = t >> 6;           // wave 0..3
  const int wr = w >> 1, wc = w & 1;
  const int l = blockIdx.x;
  const int xcd = l & 7, s = l >> 3;
  const int mat = s >> 6, inner = s & 63;
  const int m0 = (xcd*8 + (inner & 7)) * 128;
  const int n0 = (inner >> 3) * 128;
  const u16* W = Wall + (size_t)mat*E_*E_;
  const float* bias = (mat == 0) ? bq : (mat == 1) ? bk : bv;
  u16* out = (mat == 0) ? Qb : (mat == 1) ? Kb : Vtb;
  const float scale = (mat == 0) ? qscale : 1.0f;
  const int mode = (mat == 2);
  const int l15 = lane & 15, lhi = lane >> 4;

  f32x4 acc[4][4] = {};

  const int eo0 = w*1024 + lane*8;
  const u16* Ab0 = A + (size_t)(m0 + (eo0 >> 5))*E_ + (eo0 & 31);
  const u16* Wb0 = W + (size_t)(n0 + (eo0 >> 5))*E_ + (eo0 & 31);
  const int eo1 = eo0 + 512;
  const u16* Ab1 = A + (size_t)(m0 + (eo1 >> 5))*E_ + (eo1 & 31);
  const u16* Wb1 = W + (size_t)(n0 + (eo1 >> 5))*E_ + (eo1 & 31);

  auto stage = [&](int bufi, int k0) {
    GLD16(Ab0 + k0, As + bufi*4096 + w*1024);
    GLD16(Wb0 + k0, Bs + bufi*4096 + w*1024);
    GLD16(Ab1 + k0, As + bufi*4096 + w*1024 + 512);
    GLD16(Wb1 + k0, Bs + bufi*4096 + w*1024 + 512);
  };

  stage(0, 0);
  __syncthreads();
  for (int kt = 0; kt < E_/32; ++kt) {
    if (kt + 1 < E_/32) stage((kt+1)&1, (kt+1)*32);
    const u16* Ab = As + (kt&1)*4096;
    const u16* Bb = Bs + (kt&1)*4096;
    bf16x8 af[4], bfr[4];
#pragma unroll
    for (int i = 0; i < 4; ++i)
      af[i] = *(const bf16x8*)&Ab[(wr*64 + i*16 + l15)*32 + lhi*8];
#pragma unroll
    for (int i = 0; i < 4; ++i)
      bfr[i] = *(const bf16x8*)&Bb[(wc*64 + i*16 + l15)*32 + lhi*8];
    __builtin_amdgcn_s_setprio(1);
#pragma unroll
    for (int mi = 0; mi < 4; ++mi)
#pragma unroll
      for (int ni = 0; ni < 4; ++ni)
        acc[mi][ni] = __builtin_amdgcn_mfma_f32_16x16x32_bf16(af[mi], bfr[ni], acc[mi][ni], 0, 0, 0);
    __builtin_amdgcn_s_setprio(0);
    __syncthreads();
  }

  // epilogue
#pragma unroll
  for (int mi = 0; mi < 4; ++mi) {
#pragma unroll
    for (int ni = 0; ni < 4; ++ni) {
      int n = n0 + wc*64 + ni*16 + l15;
      float bia = bias[n];
      int h = n >> 6, d = n & 63;
      if (mode == 0) {
#pragma unroll
        for (int j = 0; j < 4; ++j) {
          int m = m0 + wr*64 + mi*16 + lhi*4 + j;
          int b = m >> 11, sq = m & 2047;
          out[((size_t)((b*H_ + h)*S_ + sq))*D_ + d] = f2bf((acc[mi][ni][j] + bia) * scale);
        }
      } else {
        int m = m0 + wr*64 + mi*16 + lhi*4;
        int b = m >> 11, sq = m & 2047;
        u16 pk0 = f2bf((acc[mi][ni][0] + bia) * scale);
        u16 pk1 = f2bf((acc[mi][ni][1] + bia) * scale);
        u16 pk2 = f2bf((acc[mi][ni][2] + bia) * scale);
        u16 pk3 = f2bf((acc[mi][ni][3] + bia) * scale);
        u16* p = &out[((size_t)((b*H_ + h)*D_ + d))*S_ + sq];
        p[0]=pk0; p[1]=pk1; p[2]=pk2; p[3]=pk3;
      }
    }
  }
}

// ---------------- fused causal+pad flash attention ----------------
// Q,K: [BH][S][D] bf16 (Q pre-scaled by log2e/sqrt(D)); Vt: [BH][D][S] bf16
// QB=128 (8 waves), KB=64. 1D grid, XCD-local per head: bh%8 == xcd.
// Swapped QK^T: sc[f][j] = S[q_local = w*16+l15][kv_local = f*16+lhi*4+j]
#define QB 128
#define KB 64
#define NQT (S_/QB)   // 16
__launch_bounds__(512)
__global__ void attn(const u16* __restrict__ Q, const u16* __restrict__ Kg,
                     const u16* __restrict__ Vt, const float* __restrict__ padf,
                     float* __restrict__ out) {
  __shared__ __align__(16) u16 Ks[2*KB*64];   // 2 x [64 kv][64 d], swizzled
  __shared__ __align__(16) u16 Vs[2*64*KB];   // 2 x [64 d][64 kv], swizzled
  __shared__ __align__(16) u16 Ps[8*16*64];   // per-wave P [16 q][64 kv], swizzled
  const int t = threadIdx.x, lane = t & 63, w = t >> 6;   // w 0..7
  const int l15 = lane & 15, lhi = lane >> 4;
  // XCD-local decode: xcd = l&7 gets heads bh ≡ xcd (mod 8)
  const int l = blockIdx.x;                   // 512 blocks
  const int bh = (l & 7) + 8 * (l >> 6);
  const int xt = (l >> 3) & 7;                // q-tile pair index 0..7
  const int b = bh >> 4, h = bh & 15;
  const int lsw = ((lane >> 3) & 7) << 3;     // staging swizzle (elem units)
  const int key = l15 & 7;
  const int x0 = ((0 + lhi) ^ key) * 8;       // K/V fragment col offsets (elems)
  const int x1 = ((4 + lhi) ^ key) * 8;
  // Ps offsets (elem units); XOR key on byte bits 4..6
  const int pw = w*1024 + l15*64;
  const int pxk = key << 4;
  int pwr[4], prd0, prd1;
#pragma unroll
  for (int f = 0; f < 4; ++f) pwr[f] = pw + (((f*32 + lhi*8) ^ pxk) >> 1);
  prd0 = pw + (((      lhi*16) ^ pxk) >> 1);
  prd1 = pw + (((64 +  lhi*16) ^ pxk) >> 1);

  const float* padb = padf + b*S_;

  // ones fragment for row-sum via MFMA
  bf16x8 ones;
#pragma unroll
  for (int i = 0; i < 8; ++i) ones[i] = (__bf16)1.0f;

  // hoisted staging addresses (loop: += const)
  const int leo = (t*8) ^ lsw;
  const u16* Kls = Kg + (size_t)bh*S_*D_ + leo;
  const u16* Vls = Vt + (size_t)bh*D_*S_ + (size_t)(leo >> 6)*S_ + (leo & 63);
  u16* KsD = Ks + t*8;
  u16* VsD = Vs + t*8;

  for (int half = 0; half < 2; ++half) {
    const int qt = half ? (NQT - 1 - xt) : xt;
    const int q0 = qt * QB;
    const int nkt = 2*(qt + 1);               // KB=64 tiles covering [0, q0+QB)

    // Q fragments direct from global (read exactly once)
    const u16* Qrow = Q + (size_t)(bh*S_ + q0 + w*16 + l15)*D_;
    bf16x8 qa0 = *(const bf16x8*)(Qrow + lhi*8);
    bf16x8 qa1 = *(const bf16x8*)(Qrow + 32 + lhi*8);

    f32x4 o[4] = {};
    f32x4 ls = {};
    float mrow = -1e30f;

    GLD16(Kls, KsD);
    GLD16(Vls, VsD);
    __syncthreads();
    for (int kt = 0; kt < nkt; ++kt) {
      if (kt + 1 < nkt) {
        const int nb = (kt+1)&1, nkv = (kt+1)*KB;
        GLD16(Kls + nkv*D_, KsD + nb*4096);
        GLD16(Vls + nkv,    VsD + nb*4096);
      }
      const u16* Kb_ = Ks + (kt&1)*4096;
      const u16* Vb_ = Vs + (kt&1)*4096;
      const int kv0 = kt*KB;

      // S^T = K Q^T : lane holds sc[f][j] = S[q_local][kv_local=f*16+lhi*4+j]
      f32x4 sc[4];
      __builtin_amdgcn_s_setprio(1);
#pragma unroll
      for (int f = 0; f < 4; ++f) {
        const u16* kr = Kb_ + (f*16 + l15)*64;
        f32x4 z = {};
        z = __builtin_amdgcn_mfma_f32_16x16x32_bf16(*(const bf16x8*)(kr + x0), qa0, z, 0, 0, 0);
        z = __builtin_amdgcn_mfma_f32_16x16x32_bf16(*(const bf16x8*)(kr + x1), qa1, z, 0, 0, 0);
        sc[f] = z;
      }
      __builtin_amdgcn_s_setprio(0);
      // causal mask on the last two tiles (q_local = w*16 + l15)
      if (kt >= nkt - 2) {
        const int rel = q0 + w*16 + l15 - kv0;   // mask kv_local > rel
#pragma unroll
        for (int f = 0; f < 4; ++f)
#pragma unroll
          for (int j = 0; j < 4; ++j)
            if (f*16 + lhi*4 + j > rel) sc[f][j] = -1e30f;
      }
      // row max: balanced tree (v_max3-friendly), then cross-lhi
      float mx0 = fmaxf(fmaxf(sc[0][0], sc[0][1]), fmaxf(sc[0][2], sc[0][3]));
      float mx1 = fmaxf(fmaxf(sc[1][0], sc[1][1]), fmaxf(sc[1][2], sc[1][3]));
      float mx2 = fmaxf(fmaxf(sc[2][0], sc[2][1]), fmaxf(sc[2][2], sc[2][3]));
      float mx3 = fmaxf(fmaxf(sc[3][0], sc[3][1]), fmaxf(sc[3][2], sc[3][3]));
      float pmax = fmaxf(fmaxf(mx0, mx1), fmaxf(mx2, mx3));
      pmax = fmaxf(pmax, __shfl_xor(pmax, 16));
      pmax = fmaxf(pmax, __shfl_xor(pmax, 32));
      // defer-max: rescale only when max grew by > 8 (log2 domain)
      if (__any(pmax > mrow + 8.0f)) {
        float mnew = fmaxf(mrow, pmax);
        float corr = fexp2(mrow - mnew);
        mrow = mnew;
        float cr[4];
#pragma unroll
        for (int j = 0; j < 4; ++j) cr[j] = __shfl(corr, lhi*4 + j);
#pragma unroll
        for (int df = 0; df < 4; ++df)
#pragma unroll
          for (int j = 0; j < 4; ++j) o[df][j] *= cr[j];
#pragma unroll
        for (int j = 0; j < 4; ++j) ls[j] *= cr[j];
      }
      // exp2 + pad multiply + pack P
#pragma unroll
      for (int f = 0; f < 4; ++f) {
        float4 pf = *(const float4*)(padb + kv0 + f*16 + lhi*4);
        bf16x4 pk;
        pk[0] = (__bf16)(fexp2(sc[f][0] - mrow) * pf.x);
        pk[1] = (__bf16)(fexp2(sc[f][1] - mrow) * pf.y);
        pk[2] = (__bf16)(fexp2(sc[f][2] - mrow) * pf.z);
        pk[3] = (__bf16)(fexp2(sc[f][3] - mrow) * pf.w);
        *(bf16x4*)(Ps + pwr[f]) = pk;
      }
      // PV (+ ones-column MFMA accumulates the row-sum in o-layout)
      bf16x8 pa0 = *(const bf16x8*)(Ps + prd0);
      bf16x8 pa1 = *(const bf16x8*)(Ps + prd1);
      __builtin_amdgcn_s_setprio(1);
      ls = __builtin_amdgcn_mfma_f32_16x16x32_bf16(pa0, ones, ls, 0, 0, 0);
      ls = __builtin_amdgcn_mfma_f32_16x16x32_bf16(pa1, ones, ls, 0, 0, 0);
#pragma unroll
      for (int df = 0; df < 4; ++df) {
        const u16* vr = Vb_ + (df*16 + l15)*64;
        o[df] = __builtin_amdgcn_mfma_f32_16x16x32_bf16(pa0, *(const bf16x8*)(vr + x0), o[df], 0, 0, 0);
        o[df] = __builtin_amdgcn_mfma_f32_16x16x32_bf16(pa1, *(const bf16x8*)(vr + x1), o[df], 0, 0, 0);
      }
      __builtin_amdgcn_s_setprio(0);
      __syncthreads();
    }

    // epilogue (ls is already in o-layout: row j, col l15)
#pragma unroll
    for (int j = 0; j < 4; ++j) {
      int q = q0 + w*16 + lhi*4 + j;
      float lr = ls[j];
      float pq = padb[q];
      float inv = (lr > 0.f) ? pq / lr : 0.f;
#pragma unroll
      for (int df = 0; df < 4; ++df)
        out[((size_t)(b*S_ + q))*E_ + h*D_ + df*16 + l15] = o[df][j] * inv;
    }
  }
}

extern "C" void kernel_launch(void* const* d_in, const int* in_sizes, int n_in,
                              void* d_out, int out_size, void* d_ws, size_t ws_size,
                              hipStream_t stream) {
  const float* X  = (const float*)d_in[0];
  const int*  pad = (const int*)d_in[1];
  const float* Wq = (const float*)d_in[2];
  const float* bq = (const float*)d_in[3];
  const float* Wk = (const float*)d_in[4];
  const float* bk = (const float*)d_in[5];
  const float* Wv = (const float*)d_in[6];
  const float* bv = (const float*)d_in[7];
  float* out = (float*)d_out;

  u16* Xb  = (u16*)d_ws;                         // 16 MB
  u16* Wb  = Xb + (size_t)M_*E_;                 // 6 MB (3 matrices)
  u16* Qb  = Wb + (size_t)3*E_*E_;               // 16 MB
  u16* Kb  = Qb + (size_t)M_*E_;                 // 16 MB
  u16* Vtb = Kb + (size_t)M_*E_;                 // 16 MB
  float* padfb = (float*)(Vtb + (size_t)M_*E_);  // 32 KB

  cvt_all<<<5664, 256, 0, stream>>>(X, Wq, Wk, Wv, pad, Xb, Wb, padfb);

  // Q pre-scaled by (1/sqrt(D)) * log2(e) so attention exp is pure exp2
  qkv_gemm3<<<1536, 256, 0, stream>>>(Xb, Wb, bq, bk, bv, Qb, Kb, Vtb, 0.18033688f);

  attn<<<512, 512, 0, stream>>>(Qb, Kb, Vtb, padfb, out);
}